// Round 5
// baseline (705.704 us; speedup 1.0000x reference)
//
#include <hip/hip_runtime.h>
#include <hip/hip_bf16.h>

typedef unsigned short u16;
typedef __attribute__((ext_vector_type(4))) float f32x4;
typedef __attribute__((ext_vector_type(8))) short bf16x8;
typedef __attribute__((ext_vector_type(8))) unsigned short u16x8;

#define B_    64
#define T_    2048
#define HID_  512
#define HCLS_ 1024
#define DOUT_ 10
#define M_    (B_ * T_)   // 131072 rows

// ---------- helpers ----------
__device__ __forceinline__ unsigned f2bf2(float a, float b) {
#if __has_builtin(__builtin_amdgcn_cvt_pk_bf16_f32)
  auto r = __builtin_amdgcn_cvt_pk_bf16_f32(a, b);
  unsigned u;
  __builtin_memcpy(&u, &r, 4);
  return u;
#else
  unsigned ua = __float_as_uint(a) + 0x8000u;
  unsigned ub = __float_as_uint(b) + 0x8000u;
  return __builtin_amdgcn_perm(ub, ua, 0x07060302);
#endif
}

__device__ __forceinline__ float fast_tanh(float x) {
  float e = __expf(2.0f * x);
  return 1.0f - __fdividef(2.0f, e + 1.0f);
}

// ---------- kernel 0: W [k,n] fp32 -> Wt2: MFMA-frag-contiguous bf16 ----------
// Wt2 unit = (jt, ks): 64 lanes x 16 B; lane l holds W[k0 + (l>>4)*8 ..][n = jt*16 + (l&15)]
// Used as the A-operand in v4 (A/B frag layouts are lane-symmetric) — layout unchanged.
__global__ __launch_bounds__(256) void cvt_w_kernel(const float* __restrict__ W,
                                                    u16* __restrict__ Wt2) {
  const int pair = blockIdx.x * 4 + (threadIdx.x >> 6);  // 0..511 = jt*16+ks
  const int l = threadIdx.x & 63;
  const int jt = pair >> 4, ks = pair & 15;
  const int n = jt * 16 + (l & 15);
  const int k0 = ks * 32 + (l >> 4) * 8;
  union { unsigned u[4]; u16x8 v; } r;
#pragma unroll
  for (int j = 0; j < 4; ++j)
    r.u[j] = f2bf2(W[(size_t)(k0 + 2 * j) * HID_ + n],
                   W[(size_t)(k0 + 2 * j + 1) * HID_ + n]);
  *(u16x8*)(Wt2 + (size_t)pair * 512 + l * 8) = r.v;
}

// ---------- kernel 1: barrier-free register GEMM + tanh-dot + exp + weighted-E ----------
// v4 (v1/v3 post-mortem: per-block time is a constant ~43us = 16 barrier-delimited K-phases
// x ~6400cy each, with every pipe <35% busy -> phase/barrier-drain bound, not any throughput).
// Fix: compute u^T = (W as A-operand) x (E as B-operand). E streams from GLOBAL directly into
// B-fragments (lane l: row m0+j*16+(l&15), cols ks*32+(l>>4)*8..+8 = 2 float4 + cvt_pk).
// All 8 waves read the same E bytes -> L1 broadcast. ZERO LDS / ZERO barriers in the K-loop;
// 2 barriers total (epilogue). Blocks co-schedule freely (LDS ~2.5 KB).
// D layout (col=l&15, row=(l>>4)*4+r) now gives col=m, row=n; epilogue reduces accordingly.
__global__ __launch_bounds__(512, 3) void gemm_fused_kernel(
    const float* __restrict__ E, const u16* __restrict__ Wt2,
    const float* __restrict__ bias, const float* __restrict__ cw,
    float* __restrict__ num, float* __restrict__ den) {
  __shared__ float red[8 * 64];
  __shared__ float earr[64];

  const int tid = threadIdx.x;
  const int m0 = blockIdx.x * 64;
  const int b = blockIdx.x >> 5;    // 32 blocks per batch element
  const int w = tid >> 6, l = tid & 63;
  const int lm = l & 15, lg = l >> 4;

  // E B-frag pointer: lane l, m-frag j -> row m0 + j*16 + lm, col base lg*8 (+ks*32)
  const float* eb0 = E + (size_t)(m0 + lm) * HID_ + lg * 8;
  // W A-frags from Wt2 (frag-contiguous; wave w owns n = w*64..+63 via jt = w*4+i)
  const u16* abase = Wt2 + (size_t)w * 32768 + (size_t)l * 8;

  f32x4 acc[4][4] = {};     // [i = n-frag][j = m-frag]
  float4 er[4][2];          // raw fp32 E for one K-step (refilled each step)
  bf16x8 av0[4], av1[4];    // W frags, 2-step rotation

  // prologue: er <- ks=0; av0 <- ks=0; av1 <- ks=1
#pragma unroll
  for (int j = 0; j < 4; ++j) {
    er[j][0] = *(const float4*)(eb0 + (size_t)j * 16 * HID_);
    er[j][1] = *(const float4*)(eb0 + (size_t)j * 16 * HID_ + 4);
  }
#pragma unroll
  for (int i = 0; i < 4; ++i) av0[i] = *(const bf16x8*)(abase + i * 8192);
#pragma unroll
  for (int i = 0; i < 4; ++i) av1[i] = *(const bf16x8*)(abase + i * 8192 + 512);

#pragma unroll 1
  for (int ks = 0; ks < 16; ks += 2) {
    {   // step ks: cvt er -> bf, refill er with ks+1, MFMA with av0, refill av0 with ks+2
      bf16x8 bf[4];
#pragma unroll
      for (int j = 0; j < 4; ++j) {
        union { unsigned u[4]; bf16x8 v; } t;
        t.u[0] = f2bf2(er[j][0].x, er[j][0].y);
        t.u[1] = f2bf2(er[j][0].z, er[j][0].w);
        t.u[2] = f2bf2(er[j][1].x, er[j][1].y);
        t.u[3] = f2bf2(er[j][1].z, er[j][1].w);
        bf[j] = t.v;
      }
#pragma unroll
      for (int j = 0; j < 4; ++j) {   // ks+1 <= 15 always here
        er[j][0] = *(const float4*)(eb0 + (size_t)j * 16 * HID_ + (ks + 1) * 32);
        er[j][1] = *(const float4*)(eb0 + (size_t)j * 16 * HID_ + (ks + 1) * 32 + 4);
      }
#pragma unroll
      for (int i = 0; i < 4; ++i)
#pragma unroll
        for (int j = 0; j < 4; ++j)
          acc[i][j] = __builtin_amdgcn_mfma_f32_16x16x32_bf16(av0[i], bf[j], acc[i][j], 0, 0, 0);
      if (ks + 2 < 16) {
#pragma unroll
        for (int i = 0; i < 4; ++i)
          av0[i] = *(const bf16x8*)(abase + i * 8192 + (size_t)(ks + 2) * 512);
      }
    }
    {   // step ks+1: cvt er -> bf, refill er with ks+2, MFMA with av1, refill av1 with ks+3
      bf16x8 bf[4];
#pragma unroll
      for (int j = 0; j < 4; ++j) {
        union { unsigned u[4]; bf16x8 v; } t;
        t.u[0] = f2bf2(er[j][0].x, er[j][0].y);
        t.u[1] = f2bf2(er[j][0].z, er[j][0].w);
        t.u[2] = f2bf2(er[j][1].x, er[j][1].y);
        t.u[3] = f2bf2(er[j][1].z, er[j][1].w);
        bf[j] = t.v;
      }
      if (ks + 2 < 16) {
#pragma unroll
        for (int j = 0; j < 4; ++j) {
          er[j][0] = *(const float4*)(eb0 + (size_t)j * 16 * HID_ + (ks + 2) * 32);
          er[j][1] = *(const float4*)(eb0 + (size_t)j * 16 * HID_ + (ks + 2) * 32 + 4);
        }
      }
#pragma unroll
      for (int i = 0; i < 4; ++i)
#pragma unroll
        for (int j = 0; j < 4; ++j)
          acc[i][j] = __builtin_amdgcn_mfma_f32_16x16x32_bf16(av1[i], bf[j], acc[i][j], 0, 0, 0);
      if (ks + 3 < 16) {
#pragma unroll
        for (int i = 0; i < 4; ++i)
          av1[i] = *(const bf16x8*)(abase + i * 8192 + (size_t)(ks + 3) * 512);
      }
    }
  }

  // ---- epilogue: scores partial. lane holds u^T[n][m]: m = j*16+lm, n = w*64+i*16+lg*4+r ----
  float s[4] = {0.f, 0.f, 0.f, 0.f};
#pragma unroll
  for (int i = 0; i < 4; ++i) {
#pragma unroll
    for (int r = 0; r < 4; ++r) {
      const int n = w * 64 + i * 16 + lg * 4 + r;
      const float bn = bias[n], cn = cw[n];
#pragma unroll
      for (int j = 0; j < 4; ++j)
        s[j] = fmaf(fast_tanh(acc[i][j][r] + bn), cn, s[j]);
    }
  }
  // reduce over lanes with the same m (lg varies): xor 16, 32
#pragma unroll
  for (int j = 0; j < 4; ++j) {
    s[j] += __shfl_xor(s[j], 16, 64);
    s[j] += __shfl_xor(s[j], 32, 64);
  }
  if (lg == 0) {
#pragma unroll
    for (int j = 0; j < 4; ++j) red[w * 64 + j * 16 + lm] = s[j];
  }
  __syncthreads();
  if (tid < 64) {
    float d = 0.f;
#pragma unroll
    for (int ww = 0; ww < 8; ++ww) d += red[ww * 64 + tid];
    float e = __expf(fast_tanh(d));   // tanh in (-1,1): exp safe, no max-subtract
    earr[tid] = e;
    float se = e;
    se += __shfl_xor(se, 1, 64);
    se += __shfl_xor(se, 2, 64);
    se += __shfl_xor(se, 4, 64);
    se += __shfl_xor(se, 8, 64);
    se += __shfl_xor(se, 16, 64);
    se += __shfl_xor(se, 32, 64);
    if (tid == 0) atomicAdd(den + b, se);
  }
  __syncthreads();
  // weighted-E: num[b][col] += sum_r earr[r] * E[m0+r][col]; fp32 E re-read (L2-warm), coalesced
  {
    float a = 0.f;
    const float* ec = E + (size_t)m0 * HID_ + tid;
#pragma unroll 8
    for (int r = 0; r < 64; ++r)
      a = fmaf(earr[r], ec[(size_t)r * HID_], a);
    atomicAdd(num + (size_t)b * HID_ + tid, a);
  }
}

// ---------- kernel 2: classifier: ctx=num/den -> relu(ctx@W1+b1)@W2+b2 -> softmax(10) ----------
__global__ __launch_bounds__(1024) void classifier_kernel(
    const float* __restrict__ num, const float* __restrict__ den,
    const float* __restrict__ W1, const float* __restrict__ b1,
    const float* __restrict__ W2, const float* __restrict__ b2,
    float* __restrict__ out) {
  __shared__ float sc[HID_];
  __shared__ float hbuf[HCLS_];
  __shared__ float lgs[DOUT_];
  int b = blockIdx.x, tid = threadIdx.x;
  if (tid < HID_) sc[tid] = num[(size_t)b * HID_ + tid] / den[b];
  __syncthreads();
  float a = b1[tid];
#pragma unroll 16
  for (int k = 0; k < HID_; ++k) a = fmaf(sc[k], W1[(size_t)k * HCLS_ + tid], a);
  hbuf[tid] = fmaxf(a, 0.f);
  __syncthreads();
  if (tid < 160) {   // 10 logits x 16 lanes
    int j = tid >> 4, p = tid & 15;
    float acc2 = 0.f;
#pragma unroll 8
    for (int k = p; k < HCLS_; k += 16) acc2 = fmaf(hbuf[k], W2[(size_t)k * DOUT_ + j], acc2);
    acc2 += __shfl_xor(acc2, 1, 64);
    acc2 += __shfl_xor(acc2, 2, 64);
    acc2 += __shfl_xor(acc2, 4, 64);
    acc2 += __shfl_xor(acc2, 8, 64);
    if (p == 0) lgs[j] = acc2 + b2[j];
  }
  __syncthreads();
  if (tid == 0) {
    float mx = lgs[0];
#pragma unroll
    for (int j = 1; j < DOUT_; ++j) mx = fmaxf(mx, lgs[j]);
    float ex[DOUT_], s = 0.f;
#pragma unroll
    for (int j = 0; j < DOUT_; ++j) { ex[j] = __expf(lgs[j] - mx); s += ex[j]; }
    float inv = 1.f / s;
#pragma unroll
    for (int j = 0; j < DOUT_; ++j) out[b * DOUT_ + j] = ex[j] * inv;
  }
}

// ---------- launch ----------
extern "C" void kernel_launch(void* const* d_in, const int* in_sizes, int n_in,
                              void* d_out, int out_size, void* d_ws, size_t ws_size,
                              hipStream_t stream) {
  (void)in_sizes; (void)n_in; (void)out_size; (void)ws_size;
  const float* E    = (const float*)d_in[1];
  const float* W    = (const float*)d_in[2];
  const float* bias = (const float*)d_in[3];
  const float* cw   = (const float*)d_in[4];
  const float* W1   = (const float*)d_in[5];
  const float* b1   = (const float*)d_in[6];
  const float* W2   = (const float*)d_in[7];
  const float* b2   = (const float*)d_in[8];
  float* out = (float*)d_out;

  // ws: Wt2 512K | num 128K | den 256B  (num+den zeroed each call for the atomics)
  u16*   Wt2 = (u16*)d_ws;
  float* num = (float*)((char*)d_ws + (512 << 10));
  float* den = (float*)((char*)d_ws + (512 << 10) + B_ * HID_ * sizeof(float));

  hipMemsetAsync(num, 0, (B_ * HID_ + B_) * sizeof(float), stream);
  cvt_w_kernel<<<128, 256, 0, stream>>>(W, Wt2);
  gemm_fused_kernel<<<M_ / 64, 512, 0, stream>>>(E, Wt2, bias, cw, num, den);
  classifier_kernel<<<B_, 1024, 0, stream>>>(num, den, W1, b1, W2, b2, out);
}